// Round 1
// baseline (353.867 us; speedup 1.0000x reference)
//
#include <hip/hip_runtime.h>

#define BB 32
#define NN 2048
#define DD 128
#define HH 8
#define KK 64

// ws layout (floats):
//   P: [8][128][128]   offset 0        (131072)
//   G: [32][128][128]  offset 131072   (524288)
//   M: [32][128][128]  offset 655360   (524288)

__device__ __forceinline__ float bf_lo(unsigned u){ return __uint_as_float(u << 16); }
__device__ __forceinline__ float bf_hi(unsigned u){ return __uint_as_float(u & 0xffff0000u); }
__device__ __forceinline__ unsigned short f2bf(float f){
  unsigned u = __float_as_uint(f);
  u += 0x7fffu + ((u >> 16) & 1u);   // RTNE
  return (unsigned short)(u >> 16);
}

// P[h] = Wq[h]^T @ Wk[h]   ([D,KQ]x[KQ,D] contraction over k)
__global__ __launch_bounds__(256) void kp(const float* __restrict__ Wq,
                                          const float* __restrict__ Wk,
                                          float* __restrict__ P){
  __shared__ float lq[32][132];
  __shared__ float lk[32][132];
  const int h = blockIdx.x, t = threadIdx.x;
  const int ti = t >> 4, tj = t & 15;
  const float* wq = Wq + h*KK*DD;
  const float* wk = Wk + h*KK*DD;
  float acc[8][8] = {};
  for (int kc = 0; kc < KK; kc += 32){
    __syncthreads();
    for (int i = t; i < 1024; i += 256){
      int r = i >> 5, c4 = (i & 31) << 2;
      *(float4*)(&lq[r][c4]) = *(const float4*)(wq + (kc+r)*DD + c4);
      *(float4*)(&lk[r][c4]) = *(const float4*)(wk + (kc+r)*DD + c4);
    }
    __syncthreads();
    for (int k = 0; k < 32; ++k){
      float a[8], bb[8];
      #pragma unroll
      for (int i = 0; i < 8; ++i) a[i] = lq[k][ti*8+i];
      #pragma unroll
      for (int j = 0; j < 8; ++j) bb[j] = lk[k][tj*8+j];
      #pragma unroll
      for (int i = 0; i < 8; ++i)
        #pragma unroll
        for (int j = 0; j < 8; ++j) acc[i][j] += a[i]*bb[j];
    }
  }
  float* Ph = P + h*DD*DD;
  for (int i = 0; i < 8; ++i)
    for (int j = 0; j < 8; ++j)
      Ph[(ti*8+i)*DD + tj*8+j] = acc[i][j];
}

// G[b] += x[b,chunk]^T @ x[b,chunk]   (256-row chunks, atomic accumulate)
__global__ __launch_bounds__(256) void kg(const float* __restrict__ x,
                                          float* __restrict__ G){
  __shared__ float xs[32][132];
  const int chunk = blockIdx.x, b = blockIdx.y, t = threadIdx.x;
  const int ti = t >> 4, tj = t & 15;
  const float* xb = x + ((size_t)b*NN + (size_t)chunk*256)*DD;
  float acc[8][8] = {};
  for (int ks = 0; ks < 256; ks += 32){
    __syncthreads();
    for (int i = t; i < 1024; i += 256){
      int r = i >> 5, c4 = (i & 31) << 2;
      *(float4*)(&xs[r][c4]) = *(const float4*)(xb + (size_t)(ks+r)*DD + c4);
    }
    __syncthreads();
    for (int k = 0; k < 32; ++k){
      float a[8], bb[8];
      #pragma unroll
      for (int i = 0; i < 8; ++i) a[i] = xs[k][ti*8+i];
      #pragma unroll
      for (int j = 0; j < 8; ++j) bb[j] = xs[k][tj*8+j];
      #pragma unroll
      for (int i = 0; i < 8; ++i)
        #pragma unroll
        for (int j = 0; j < 8; ++j) acc[i][j] += a[i]*bb[j];
    }
  }
  float* Gb = G + b*DD*DD;
  #pragma unroll
  for (int i = 0; i < 8; ++i)
    #pragma unroll
    for (int j = 0; j < 8; ++j)
      atomicAdd(&Gb[(ti*8+i)*DD + tj*8+j], acc[i][j]);
}

// per (e-half, h, b): T = G[b] @ Wv[h]^T (half of e);  M[b] += P[h] @ T  (atomic)
// bf16 LDS staging (fp32 padded 128x128 operands don't fit in 64KB)
__global__ __launch_bounds__(256) void km(const float* __restrict__ G,
                                          const float* __restrict__ Wv,
                                          const float* __restrict__ P,
                                          float* __restrict__ M){
  __shared__ unsigned short As[128*132]; // G, then P      (bf16)
  __shared__ unsigned short Bs[64*132];  // Wv-half, then T^T (bf16)
  const int eh = blockIdx.x, h = blockIdx.y, b = blockIdx.z;
  const int t = threadIdx.x;
  const int ti = t >> 4, tj = t & 15;   // d-base = ti*8 (128), e-base = tj*4 (64)
  const int e0 = eh*64;
  const float* Gb  = G + b*DD*DD;
  const float* Wvh = Wv + ((size_t)h*DD + e0)*DD;
  for (int i = t; i < 16384; i += 256)
    As[(i>>7)*132 + (i&127)] = f2bf(Gb[i]);
  for (int i = t; i < 8192; i += 256)
    Bs[(i>>7)*132 + (i&127)] = f2bf(Wvh[i]);
  __syncthreads();
  // phase 1: T[d][e'] = sum_d' G[d][d'] * Wv[e0+e'][d']
  float acc[8][4] = {};
  for (int k = 0; k < 128; k += 4){
    float av[8][4], bv[4][4];
    #pragma unroll
    for (int i = 0; i < 8; ++i){
      uint2 u = *(const uint2*)(&As[(ti*8+i)*132 + k]);
      av[i][0] = bf_lo(u.x); av[i][1] = bf_hi(u.x);
      av[i][2] = bf_lo(u.y); av[i][3] = bf_hi(u.y);
    }
    #pragma unroll
    for (int j = 0; j < 4; ++j){
      uint2 u = *(const uint2*)(&Bs[(tj*4+j)*132 + k]);
      bv[j][0] = bf_lo(u.x); bv[j][1] = bf_hi(u.x);
      bv[j][2] = bf_lo(u.y); bv[j][3] = bf_hi(u.y);
    }
    #pragma unroll
    for (int i = 0; i < 8; ++i)
      #pragma unroll
      for (int j = 0; j < 4; ++j)
        #pragma unroll
        for (int kk = 0; kk < 4; ++kk)
          acc[i][j] += av[i][kk]*bv[j][kk];
  }
  __syncthreads();
  // store T^T (bf16) into Bs; load P[h] (bf16) into As
  #pragma unroll
  for (int i = 0; i < 8; ++i)
    #pragma unroll
    for (int j = 0; j < 4; ++j)
      Bs[(tj*4+j)*132 + ti*8+i] = f2bf(acc[i][j]);
  const float* Ph = P + h*DD*DD;
  for (int i = t; i < 16384; i += 256)
    As[(i>>7)*132 + (i&127)] = f2bf(Ph[i]);
  __syncthreads();
  // phase 2: M[d][e0+e'] += sum_c P[d][c] * T[c][e']  (T^T[e'][c])
  float acc2[8][4] = {};
  for (int k = 0; k < 128; k += 4){
    float av[8][4], bv[4][4];
    #pragma unroll
    for (int i = 0; i < 8; ++i){
      uint2 u = *(const uint2*)(&As[(ti*8+i)*132 + k]);
      av[i][0] = bf_lo(u.x); av[i][1] = bf_hi(u.x);
      av[i][2] = bf_lo(u.y); av[i][3] = bf_hi(u.y);
    }
    #pragma unroll
    for (int j = 0; j < 4; ++j){
      uint2 u = *(const uint2*)(&Bs[(tj*4+j)*132 + k]);
      bv[j][0] = bf_lo(u.x); bv[j][1] = bf_hi(u.x);
      bv[j][2] = bf_lo(u.y); bv[j][3] = bf_hi(u.y);
    }
    #pragma unroll
    for (int i = 0; i < 8; ++i)
      #pragma unroll
      for (int j = 0; j < 4; ++j)
        #pragma unroll
        for (int kk = 0; kk < 4; ++kk)
          acc2[i][j] += av[i][kk]*bv[j][kk];
  }
  float* Mb = M + b*DD*DD;
  #pragma unroll
  for (int i = 0; i < 8; ++i)
    #pragma unroll
    for (int j = 0; j < 4; ++j)
      atomicAdd(&Mb[(ti*8+i)*DD + e0 + tj*4+j], acc2[i][j]);
}

// out[b,ntile] = x[b,ntile] @ M[b]   (x staged transposed [d][n] in LDS)
__global__ __launch_bounds__(256) void ko(const float* __restrict__ x,
                                          const float* __restrict__ M,
                                          float* __restrict__ out){
  __shared__ float xs[32][132];   // [d-chunk][n]
  __shared__ float Ms[32][132];   // [d-chunk][e]
  const int nt = blockIdx.x, b = blockIdx.y, t = threadIdx.x;
  const int ti = t >> 4, tj = t & 15;
  const float* xb = x + ((size_t)b*NN + (size_t)nt*128)*DD;
  const float* Mb = M + b*DD*DD;
  float acc[8][8] = {};
  for (int kc = 0; kc < 4; ++kc){
    __syncthreads();
    for (int i = t; i < 1024; i += 256){
      int n = i >> 3, dq = i & 7;
      float4 v = *(const float4*)(xb + (size_t)n*DD + kc*32 + dq*4);
      xs[dq*4+0][n] = v.x; xs[dq*4+1][n] = v.y;
      xs[dq*4+2][n] = v.z; xs[dq*4+3][n] = v.w;
    }
    for (int i = t; i < 1024; i += 256){
      int r = i >> 5, e4 = (i & 31) << 2;
      *(float4*)(&Ms[r][e4]) = *(const float4*)(Mb + (kc*32+r)*DD + e4);
    }
    __syncthreads();
    for (int k = 0; k < 32; ++k){
      float a[8], bb[8];
      #pragma unroll
      for (int i = 0; i < 8; ++i) a[i] = xs[k][ti*8+i];
      #pragma unroll
      for (int j = 0; j < 8; ++j) bb[j] = Ms[k][tj*8+j];
      #pragma unroll
      for (int i = 0; i < 8; ++i)
        #pragma unroll
        for (int j = 0; j < 8; ++j) acc[i][j] += a[i]*bb[j];
    }
  }
  float* ob = out + ((size_t)b*NN + (size_t)nt*128)*DD;
  #pragma unroll
  for (int i = 0; i < 8; ++i){
    float4 v0 = make_float4(acc[i][0],acc[i][1],acc[i][2],acc[i][3]);
    float4 v1 = make_float4(acc[i][4],acc[i][5],acc[i][6],acc[i][7]);
    *(float4*)(ob + (size_t)(ti*8+i)*DD + tj*8)     = v0;
    *(float4*)(ob + (size_t)(ti*8+i)*DD + tj*8 + 4) = v1;
  }
}

extern "C" void kernel_launch(void* const* d_in, const int* in_sizes, int n_in,
                              void* d_out, int out_size, void* d_ws, size_t ws_size,
                              hipStream_t stream){
  const float* x  = (const float*)d_in[0];
  const float* Wk = (const float*)d_in[1];
  const float* Wq = (const float*)d_in[2];
  const float* Wv = (const float*)d_in[3];
  float* out = (float*)d_out;
  float* P = (float*)d_ws;
  float* G = P + 131072;
  float* M = G + 524288;
  // zero G and M (ws is poisoned 0xAA before every launch)
  hipMemsetAsync(G, 0, (size_t)(524288 + 524288)*sizeof(float), stream);
  kp<<<8, 256, 0, stream>>>(Wq, Wk, P);
  kg<<<dim3(8,32), 256, 0, stream>>>(x, G);
  km<<<dim3(2,8,32), 256, 0, stream>>>(G, Wv, P, M);
  ko<<<dim3(16,32), 256, 0, stream>>>(x, M, out);
}

// Round 2
// 202.519 us; speedup vs baseline: 1.7473x; 1.7473x over previous
//
#include <hip/hip_runtime.h>

#define BB 32
#define NN 2048
#define DD 128
#define HH 8
#define KK 64

// ws layout (floats):
//   P : [8][128][128]        @ 0        (131072)
//   G : [32][128][128]       @ 131072   (524288)
//   M : [32][128][128]       @ 655360   (524288)
//   Gp: [16][32][128][128]   @ 1179648  (8388608)   partial-G (big-ws path)
//   Mp: [32][8][128][128]    @ 9568256  (4194304)   partial-M (big-ws path)
#define WS_NEED_FLOATS 13762560ULL

__device__ __forceinline__ float bf_lo(unsigned u){ return __uint_as_float(u << 16); }
__device__ __forceinline__ float bf_hi(unsigned u){ return __uint_as_float(u & 0xffff0000u); }
__device__ __forceinline__ unsigned short f2bf(float f){
  unsigned u = __float_as_uint(f);
  u += 0x7fffu + ((u >> 16) & 1u);   // RTNE
  return (unsigned short)(u >> 16);
}

// P[h] = Wq[h]^T @ Wk[h].  grid 32 = (h<<2 | rowtile), 32-row output tiles.
__global__ __launch_bounds__(256) void kp(const float* __restrict__ Wq,
                                          const float* __restrict__ Wk,
                                          float* __restrict__ P){
  __shared__ float Aq[64][36];    // Wq[h][k][i0+0..32]
  __shared__ float Bk[64][132];   // Wk[h][k][0..128]
  const int t = threadIdx.x;
  const int h = blockIdx.x >> 2, rt = blockIdx.x & 3;
  const int i0 = rt * 32;
  const int tr = t >> 5, tc = t & 31;   // 8 row-groups x 32 col-groups, 4x4 tile
  const float* wq = Wq + h*KK*DD;
  const float* wk = Wk + h*KK*DD;
  for (int i = t; i < 512; i += 256){           // 64x32 floats
    int k = i >> 3, c4 = (i & 7) << 2;
    *(float4*)(&Aq[k][c4]) = *(const float4*)(wq + k*DD + i0 + c4);
  }
  for (int i = t; i < 2048; i += 256){          // 64x128 floats
    int k = i >> 5, c4 = (i & 31) << 2;
    *(float4*)(&Bk[k][c4]) = *(const float4*)(wk + k*DD + c4);
  }
  __syncthreads();
  float acc[4][4] = {};
  for (int k = 0; k < 64; k += 2){
    float a0[4], b0[4], a1[4], b1[4];
    *(float4*)a0 = *(float4*)(&Aq[k][tr*4]);
    *(float4*)b0 = *(float4*)(&Bk[k][tc*4]);
    *(float4*)a1 = *(float4*)(&Aq[k+1][tr*4]);
    *(float4*)b1 = *(float4*)(&Bk[k+1][tc*4]);
    #pragma unroll
    for (int i = 0; i < 4; ++i)
      #pragma unroll
      for (int j = 0; j < 4; ++j){
        acc[i][j] += a0[i]*b0[j];
        acc[i][j] += a1[i]*b1[j];
      }
  }
  float* Ph = P + h*DD*DD;
  #pragma unroll
  for (int i = 0; i < 4; ++i)
    *(float4*)(&Ph[(i0 + tr*4 + i)*DD + tc*4]) =
        make_float4(acc[i][0], acc[i][1], acc[i][2], acc[i][3]);
}

// G partial: per (b, chunk of 128 rows): acc = x_chunk^T @ x_chunk.
// PARTIAL=1 -> plain store to Gp[chunk][b]; PARTIAL=0 -> atomicAdd into G[b].
// 1D grid 512, b = low-5-bits swizzle so all blocks of b share an XCD (atomic path).
template<int PARTIAL>
__global__ __launch_bounds__(256) void kg(const float* __restrict__ x,
                                          float* __restrict__ Gout){
  __shared__ float xs[64][132];
  const int t = threadIdx.x;
  const int bid = blockIdx.x;
  const int b = (bid & 7) | (((bid >> 3) & 3) << 3);
  const int chunk = bid >> 5;                    // 0..15, 128 rows each
  const int ti = t >> 4, tj = t & 15;
  const float* xb = x + ((size_t)b*NN + (size_t)chunk*128)*DD;
  float acc[8][8] = {};
  for (int half = 0; half < 2; ++half){
    if (half) __syncthreads();
    for (int i = t; i < 2048; i += 256){
      int r = i >> 5, c4 = (i & 31) << 2;
      *(float4*)(&xs[r][c4]) = *(const float4*)(xb + (size_t)(half*64 + r)*DD + c4);
    }
    __syncthreads();
    for (int k = 0; k < 64; k += 2){
      float a0[8], b0[8], a1[8], b1[8];
      *(float4*)&a0[0] = *(float4*)(&xs[k][ti*8]);
      *(float4*)&a0[4] = *(float4*)(&xs[k][ti*8+4]);
      *(float4*)&b0[0] = *(float4*)(&xs[k][tj*8]);
      *(float4*)&b0[4] = *(float4*)(&xs[k][tj*8+4]);
      *(float4*)&a1[0] = *(float4*)(&xs[k+1][ti*8]);
      *(float4*)&a1[4] = *(float4*)(&xs[k+1][ti*8+4]);
      *(float4*)&b1[0] = *(float4*)(&xs[k+1][tj*8]);
      *(float4*)&b1[4] = *(float4*)(&xs[k+1][tj*8+4]);
      #pragma unroll
      for (int i = 0; i < 8; ++i)
        #pragma unroll
        for (int j = 0; j < 8; ++j){
          acc[i][j] += a0[i]*b0[j];
          acc[i][j] += a1[i]*b1[j];
        }
    }
  }
  if (PARTIAL){
    float* Gp = Gout + ((size_t)(chunk*32 + b) << 14);
    #pragma unroll
    for (int i = 0; i < 8; ++i){
      *(float4*)(&Gp[(ti*8+i)*DD + tj*8    ]) = make_float4(acc[i][0],acc[i][1],acc[i][2],acc[i][3]);
      *(float4*)(&Gp[(ti*8+i)*DD + tj*8 + 4]) = make_float4(acc[i][4],acc[i][5],acc[i][6],acc[i][7]);
    }
  } else {
    float* Gb = Gout + ((size_t)b << 14);
    #pragma unroll
    for (int i = 0; i < 8; ++i)
      #pragma unroll
      for (int j = 0; j < 8; ++j)
        atomicAdd(&Gb[(ti*8+i)*DD + tj*8+j], acc[i][j]);
  }
}

// G[b] = sum_p Gp[p][b]
__global__ __launch_bounds__(256) void kgr(const float* __restrict__ Gp,
                                           float* __restrict__ G){
  size_t idx = (size_t)blockIdx.x*1024 + threadIdx.x*4;
  int b = (int)(idx >> 14); int i = (int)(idx & 16383);
  float4 s = make_float4(0.f,0.f,0.f,0.f);
  #pragma unroll
  for (int p = 0; p < 16; ++p){
    float4 v = *(const float4*)(Gp + ((size_t)(p*32 + b) << 14) + i);
    s.x += v.x; s.y += v.y; s.z += v.z; s.w += v.w;
  }
  *(float4*)(G + idx) = s;
}

// per (b,h,eh): T = G[b] @ Wv[h]^T (e-half); then P[h] @ T.
// PARTIAL=1 -> store into Mp[b][h]; PARTIAL=0 -> atomicAdd into M[b].
// 1D grid 512: b from low 5 bits (XCD swizzle + G[b] L2 reuse).
template<int PARTIAL>
__global__ __launch_bounds__(256) void km(const float* __restrict__ G,
                                          const float* __restrict__ Wv,
                                          const float* __restrict__ P,
                                          float* __restrict__ Mout){
  __shared__ unsigned short As[128*132]; // G, then P        (bf16)
  __shared__ unsigned short Bs[64*132];  // Wv-half, then T^T (bf16)
  const int bid = blockIdx.x;
  const int b  = (bid & 7) | (((bid >> 3) & 3) << 3);
  const int h  = (bid >> 5) & 7;
  const int eh = bid >> 8;
  const int t = threadIdx.x;
  const int ti = t >> 4, tj = t & 15;
  const int e0 = eh*64;
  const float* Gb  = G + ((size_t)b << 14);
  const float* Wvh = Wv + ((size_t)h*DD + e0)*DD;
  for (int i = t; i < 16384; i += 256)
    As[(i>>7)*132 + (i&127)] = f2bf(Gb[i]);
  for (int i = t; i < 8192; i += 256)
    Bs[(i>>7)*132 + (i&127)] = f2bf(Wvh[i]);
  __syncthreads();
  float acc[8][4] = {};
  for (int k = 0; k < 128; k += 4){
    float av[8][4], bv[4][4];
    #pragma unroll
    for (int i = 0; i < 8; ++i){
      uint2 u = *(const uint2*)(&As[(ti*8+i)*132 + k]);
      av[i][0] = bf_lo(u.x); av[i][1] = bf_hi(u.x);
      av[i][2] = bf_lo(u.y); av[i][3] = bf_hi(u.y);
    }
    #pragma unroll
    for (int j = 0; j < 4; ++j){
      uint2 u = *(const uint2*)(&Bs[(tj*4+j)*132 + k]);
      bv[j][0] = bf_lo(u.x); bv[j][1] = bf_hi(u.x);
      bv[j][2] = bf_lo(u.y); bv[j][3] = bf_hi(u.y);
    }
    #pragma unroll
    for (int i = 0; i < 8; ++i)
      #pragma unroll
      for (int j = 0; j < 4; ++j)
        #pragma unroll
        for (int kk = 0; kk < 4; ++kk)
          acc[i][j] += av[i][kk]*bv[j][kk];
  }
  __syncthreads();
  #pragma unroll
  for (int i = 0; i < 8; ++i)
    #pragma unroll
    for (int j = 0; j < 4; ++j)
      Bs[(tj*4+j)*132 + ti*8+i] = f2bf(acc[i][j]);
  const float* Ph = P + h*DD*DD;
  for (int i = t; i < 16384; i += 256)
    As[(i>>7)*132 + (i&127)] = f2bf(Ph[i]);
  __syncthreads();
  float acc2[8][4] = {};
  for (int k = 0; k < 128; k += 4){
    float av[8][4], bv[4][4];
    #pragma unroll
    for (int i = 0; i < 8; ++i){
      uint2 u = *(const uint2*)(&As[(ti*8+i)*132 + k]);
      av[i][0] = bf_lo(u.x); av[i][1] = bf_hi(u.x);
      av[i][2] = bf_lo(u.y); av[i][3] = bf_hi(u.y);
    }
    #pragma unroll
    for (int j = 0; j < 4; ++j){
      uint2 u = *(const uint2*)(&Bs[(tj*4+j)*132 + k]);
      bv[j][0] = bf_lo(u.x); bv[j][1] = bf_hi(u.x);
      bv[j][2] = bf_lo(u.y); bv[j][3] = bf_hi(u.y);
    }
    #pragma unroll
    for (int i = 0; i < 8; ++i)
      #pragma unroll
      for (int j = 0; j < 4; ++j)
        #pragma unroll
        for (int kk = 0; kk < 4; ++kk)
          acc2[i][j] += av[i][kk]*bv[j][kk];
  }
  if (PARTIAL){
    float* Mb = Mout + ((size_t)(b*8 + h) << 14);
    #pragma unroll
    for (int i = 0; i < 8; ++i)
      *(float4*)(&Mb[(ti*8+i)*DD + e0 + tj*4]) =
          make_float4(acc2[i][0], acc2[i][1], acc2[i][2], acc2[i][3]);
  } else {
    float* Mb = Mout + ((size_t)b << 14);
    #pragma unroll
    for (int i = 0; i < 8; ++i)
      #pragma unroll
      for (int j = 0; j < 4; ++j)
        atomicAdd(&Mb[(ti*8+i)*DD + e0 + tj*4+j], acc2[i][j]);
  }
}

// M[b] = sum_h Mp[b][h]
__global__ __launch_bounds__(256) void kmr(const float* __restrict__ Mp,
                                           float* __restrict__ M){
  size_t idx = (size_t)blockIdx.x*1024 + threadIdx.x*4;
  int b = (int)(idx >> 14); int i = (int)(idx & 16383);
  float4 s = make_float4(0.f,0.f,0.f,0.f);
  #pragma unroll
  for (int h = 0; h < 8; ++h){
    float4 v = *(const float4*)(Mp + ((size_t)(b*8 + h) << 14) + i);
    s.x += v.x; s.y += v.y; s.z += v.z; s.w += v.w;
  }
  *(float4*)(M + idx) = s;
}

// out[b, ntile] = x[b, ntile] @ M[b].  1D grid 512, b swizzled for M L2 reuse.
__global__ __launch_bounds__(256) void ko(const float* __restrict__ x,
                                          const float* __restrict__ M,
                                          float* __restrict__ out){
  __shared__ float xs[32][132];   // x chunk transposed: [d][n]
  __shared__ float Ms[32][132];   // [d][e]
  const int bid = blockIdx.x;
  const int b  = (bid & 7) | (((bid >> 3) & 3) << 3);
  const int nt = bid >> 5;
  const int t = threadIdx.x;
  const int ti = t >> 4, tj = t & 15;
  const float* xb = x + ((size_t)b*NN + (size_t)nt*128)*DD;
  const float* Mb = M + ((size_t)b << 14);
  float acc[8][8] = {};
  for (int kc = 0; kc < 4; ++kc){
    __syncthreads();
    for (int i = t; i < 1024; i += 256){
      int n = i >> 3, dq = i & 7;
      float4 v = *(const float4*)(xb + (size_t)n*DD + kc*32 + dq*4);
      xs[dq*4+0][n] = v.x; xs[dq*4+1][n] = v.y;
      xs[dq*4+2][n] = v.z; xs[dq*4+3][n] = v.w;
    }
    for (int i = t; i < 1024; i += 256){
      int r = i >> 5, e4 = (i & 31) << 2;
      *(float4*)(&Ms[r][e4]) = *(const float4*)(Mb + (kc*32+r)*DD + e4);
    }
    __syncthreads();
    for (int k = 0; k < 32; k += 2){
      float a0[8], b0[8], a1[8], b1[8];
      *(float4*)&a0[0] = *(float4*)(&xs[k][ti*8]);
      *(float4*)&a0[4] = *(float4*)(&xs[k][ti*8+4]);
      *(float4*)&b0[0] = *(float4*)(&Ms[k][tj*8]);
      *(float4*)&b0[4] = *(float4*)(&Ms[k][tj*8+4]);
      *(float4*)&a1[0] = *(float4*)(&xs[k+1][ti*8]);
      *(float4*)&a1[4] = *(float4*)(&xs[k+1][ti*8+4]);
      *(float4*)&b1[0] = *(float4*)(&Ms[k+1][tj*8]);
      *(float4*)&b1[4] = *(float4*)(&Ms[k+1][tj*8+4]);
      #pragma unroll
      for (int i = 0; i < 8; ++i)
        #pragma unroll
        for (int j = 0; j < 8; ++j){
          acc[i][j] += a0[i]*b0[j];
          acc[i][j] += a1[i]*b1[j];
        }
    }
  }
  float* ob = out + ((size_t)b*NN + (size_t)nt*128)*DD;
  #pragma unroll
  for (int i = 0; i < 8; ++i){
    *(float4*)(ob + (size_t)(ti*8+i)*DD + tj*8    ) = make_float4(acc[i][0],acc[i][1],acc[i][2],acc[i][3]);
    *(float4*)(ob + (size_t)(ti*8+i)*DD + tj*8 + 4) = make_float4(acc[i][4],acc[i][5],acc[i][6],acc[i][7]);
  }
}

extern "C" void kernel_launch(void* const* d_in, const int* in_sizes, int n_in,
                              void* d_out, int out_size, void* d_ws, size_t ws_size,
                              hipStream_t stream){
  const float* x  = (const float*)d_in[0];
  const float* Wk = (const float*)d_in[1];
  const float* Wq = (const float*)d_in[2];
  const float* Wv = (const float*)d_in[3];
  float* out = (float*)d_out;
  float* P  = (float*)d_ws;
  float* G  = P + 131072;
  float* M  = G + 524288;
  float* Gp = M + 524288;
  float* Mp = Gp + 8388608;
  const bool big = ws_size >= WS_NEED_FLOATS * sizeof(float);

  kp<<<32, 256, 0, stream>>>(Wq, Wk, P);
  if (big){
    kg<1><<<512, 256, 0, stream>>>(x, Gp);
    kgr<<<512, 256, 0, stream>>>(Gp, G);
    km<1><<<512, 256, 0, stream>>>(G, Wv, P, Mp);
    kmr<<<512, 256, 0, stream>>>(Mp, M);
  } else {
    hipMemsetAsync(G, 0, (size_t)(524288 + 524288)*sizeof(float), stream);
    kg<0><<<512, 256, 0, stream>>>(x, G);
    km<0><<<512, 256, 0, stream>>>(G, Wv, P, M);
  }
  ko<<<512, 256, 0, stream>>>(x, M, out);
}

// Round 3
// 128.113 us; speedup vs baseline: 2.7621x; 1.5808x over previous
//
#include <hip/hip_runtime.h>

#define BB 32
#define NN 2048
#define DD 128
#define HH 8
#define KK 64

typedef __attribute__((ext_vector_type(8))) short bf16x8;
typedef __attribute__((ext_vector_type(4))) float f32x4;
#define MFMA_BF16 __builtin_amdgcn_mfma_f32_16x16x32_bf16

// ws layout (floats):
//   Gp  : [16][32][128][128] fp32 @ 0         (8388608)
//   Mpt : [32][8][128][128]  fp32 @ 8388608   (4194304)  (stored [e][d])
//   Gbf : [32][128][128]     bf16 @ 12582912  (262144 fl)
//   Pbf : [8][128][128]      bf16 @ +262144   (65536 fl)
//   Mtbf: [32][128][128]     bf16 @ +65536    (262144 fl)  (stored [e][d])

__device__ __forceinline__ float bf2f(unsigned short h){ return __uint_as_float(((unsigned)h) << 16); }
__device__ __forceinline__ unsigned short f2bf(float f){
  unsigned u = __float_as_uint(f);
  u += 0x7fffu + ((u >> 16) & 1u);   // RTNE
  return (unsigned short)(u >> 16);
}

// swizzled frag load: layout phys_ushort(d,n) = d*128 + ((n>>3)^(d&7))*8 + (n&7)
__device__ __forceinline__ bf16x8 ldfrag_sw(const unsigned short* base, int row16, int kc, int lane){
  int d = row16 + (lane & 15);
  int q = lane >> 4;
  int ch = ((kc << 2) + q) ^ (d & 7);
  return *(const bf16x8*)(base + d*128 + ch*8);
}
// padded frag load: row stride 136 ushorts
__device__ __forceinline__ bf16x8 ldfrag_pad(const unsigned short* base, int row16, int kc, int lane){
  int r = row16 + (lane & 15);
  int q = lane >> 4;
  return *(const bf16x8*)(base + r*136 + kc*32 + q*8);
}

// ---------------- fused kg (blocks 0..511) + kp (blocks 512..543) ----------------
// kg: Gp[chunk][b] = x_chunk^T @ x_chunk  (128-row chunks, hi/lo bf16 split, MFMA)
// kp: Pbf[h] = bf16(Wq[h]^T @ Wk[h])      (fp32 vector math)
__global__ __launch_bounds__(256) void kgkp(const float* __restrict__ x,
                                            const float* __restrict__ Wq,
                                            const float* __restrict__ Wk,
                                            float* __restrict__ Gp,
                                            unsigned short* __restrict__ Pbf){
  __shared__ __align__(16) unsigned short sm[32768];   // 64 KB
  const int t = threadIdx.x;
  const int bid = blockIdx.x;
  if (bid < 512){
    unsigned short* xh = sm;            // hi, swizzled [128][128]
    unsigned short* xl = sm + 16384;    // lo
    const int b = bid & 31, chunk = bid >> 5;
    const float* xb = x + ((size_t)b*NN + (size_t)chunk*128)*DD;
    // stage: 4x4 register-transpose blocks, swizzled bf16 hi/lo writes
    for (int it = 0; it < 4; ++it){
      int gidx = it*256 + t;
      int n4g = (gidx & 7) | (((gidx >> 6) & 3) << 3);
      int dcq = ((gidx >> 3) & 7) | (((gidx >> 8) & 3) << 3);
      float4 v[4];
      #pragma unroll
      for (int j = 0; j < 4; ++j)
        v[j] = *(const float4*)(xb + (size_t)(n4g*4 + j)*DD + dcq*4);
      #pragma unroll
      for (int i = 0; i < 4; ++i){
        int d = dcq*4 + i;
        float f0 = (&v[0].x)[i], f1 = (&v[1].x)[i], f2 = (&v[2].x)[i], f3 = (&v[3].x)[i];
        unsigned short h0 = f2bf(f0), h1 = f2bf(f1), h2 = f2bf(f2), h3 = f2bf(f3);
        unsigned short l0 = f2bf(f0 - bf2f(h0)), l1 = f2bf(f1 - bf2f(h1));
        unsigned short l2 = f2bf(f2 - bf2f(h2)), l3 = f2bf(f3 - bf2f(h3));
        int off = d*128 + ((((n4g >> 1) ^ (d & 7)) << 3) + (n4g & 1)*4);
        *(ushort4*)(xh + off) = make_ushort4(h0, h1, h2, h3);
        *(ushort4*)(xl + off) = make_ushort4(l0, l1, l2, l3);
      }
    }
    __syncthreads();
    const int w = t >> 6, lane = t & 63, quad = lane >> 4;
    const int wr = (w >> 1)*64, wc = (w & 1)*64;
    f32x4 acc[4][4] = {};
    for (int kc = 0; kc < 4; ++kc){
      bf16x8 ah[4], al[4], bh[4], bl[4];
      #pragma unroll
      for (int r = 0; r < 4; ++r){
        ah[r] = ldfrag_sw(xh, wr + r*16, kc, lane);
        al[r] = ldfrag_sw(xl, wr + r*16, kc, lane);
      }
      #pragma unroll
      for (int c = 0; c < 4; ++c){
        bh[c] = ldfrag_sw(xh, wc + c*16, kc, lane);
        bl[c] = ldfrag_sw(xl, wc + c*16, kc, lane);
      }
      #pragma unroll
      for (int r = 0; r < 4; ++r)
        #pragma unroll
        for (int c = 0; c < 4; ++c){
          acc[r][c] = MFMA_BF16(ah[r], bh[c], acc[r][c], 0, 0, 0);
          acc[r][c] = MFMA_BF16(ah[r], bl[c], acc[r][c], 0, 0, 0);
          acc[r][c] = MFMA_BF16(al[r], bh[c], acc[r][c], 0, 0, 0);
        }
    }
    float* gp = Gp + ((size_t)(chunk*32 + b) << 14);
    #pragma unroll
    for (int r = 0; r < 4; ++r)
      #pragma unroll
      for (int c = 0; c < 4; ++c)
        #pragma unroll
        for (int reg = 0; reg < 4; ++reg)
          gp[(size_t)(wr + r*16 + quad*4 + reg)*DD + wc + c*16 + (lane & 15)] = acc[r][c][reg];
  } else {
    // ---- kp path ----
    float* Aq = (float*)sm;          // [64][36]
    float* Bk = Aq + 64*36;          // [64][132]
    const int kpid = bid - 512;
    const int h = kpid >> 2, rt = kpid & 3;
    const int i0 = rt * 32;
    const int tr = t >> 5, tc = t & 31;
    const float* wq = Wq + h*KK*DD;
    const float* wk = Wk + h*KK*DD;
    for (int i = t; i < 512; i += 256){
      int k = i >> 3, c4 = (i & 7) << 2;
      *(float4*)(&Aq[k*36 + c4]) = *(const float4*)(wq + k*DD + i0 + c4);
    }
    for (int i = t; i < 2048; i += 256){
      int k = i >> 5, c4 = (i & 31) << 2;
      *(float4*)(&Bk[k*132 + c4]) = *(const float4*)(wk + k*DD + c4);
    }
    __syncthreads();
    float acc[4][4] = {};
    for (int k = 0; k < 64; k += 2){
      float a0[4], b0[4], a1[4], b1[4];
      *(float4*)a0 = *(float4*)(&Aq[k*36 + tr*4]);
      *(float4*)b0 = *(float4*)(&Bk[k*132 + tc*4]);
      *(float4*)a1 = *(float4*)(&Aq[(k+1)*36 + tr*4]);
      *(float4*)b1 = *(float4*)(&Bk[(k+1)*132 + tc*4]);
      #pragma unroll
      for (int i = 0; i < 4; ++i)
        #pragma unroll
        for (int j = 0; j < 4; ++j){
          acc[i][j] += a0[i]*b0[j];
          acc[i][j] += a1[i]*b1[j];
        }
    }
    unsigned short* Ph = Pbf + h*DD*DD;
    #pragma unroll
    for (int i = 0; i < 4; ++i)
      *(ushort4*)(&Ph[(i0 + tr*4 + i)*DD + tc*4]) =
          make_ushort4(f2bf(acc[i][0]), f2bf(acc[i][1]), f2bf(acc[i][2]), f2bf(acc[i][3]));
  }
}

// ---------------- kgr: Gbf[b] = bf16( sum_p Gp[p][b] ) ----------------
__global__ __launch_bounds__(256) void kgr(const float* __restrict__ Gp,
                                           unsigned short* __restrict__ Gbf){
  size_t idx = (size_t)blockIdx.x*1024 + threadIdx.x*4;
  int b = (int)(idx >> 14); int i = (int)(idx & 16383);
  float4 s = make_float4(0.f, 0.f, 0.f, 0.f);
  #pragma unroll
  for (int p = 0; p < 16; ++p){
    float4 v = *(const float4*)(Gp + ((size_t)(p*32 + b) << 14) + i);
    s.x += v.x; s.y += v.y; s.z += v.z; s.w += v.w;
  }
  *(ushort4*)(Gbf + idx) = make_ushort4(f2bf(s.x), f2bf(s.y), f2bf(s.z), f2bf(s.w));
}

// ---------------- km: per (b,h,eh): T = G@Wv^T (e-half), Mpt[b][h] = (P@T)^T ----------------
__global__ __launch_bounds__(256) void km(const unsigned short* __restrict__ Gbf,
                                          const float* __restrict__ Wv,
                                          const unsigned short* __restrict__ Pbf,
                                          float* __restrict__ Mpt){
  __shared__ __align__(16) unsigned short As[128*136];  // G then P (bf16, pad 136); epilogue: float [64][132]
  __shared__ __align__(16) unsigned short Bs[64*136];   // Wv-half then T^T (bf16)
  const int bid = blockIdx.x;
  const int b = bid & 31, h = (bid >> 5) & 7, eh = bid >> 8;
  const int e0 = eh * 64;
  const int t = threadIdx.x;
  const int w = t >> 6, lane = t & 63, quad = lane >> 4;
  const unsigned short* Gb = Gbf + ((size_t)b << 14);
  const float* Wvh = Wv + ((size_t)h*DD + e0)*DD;
  // stage G (16B copies) and Wv-half (cvt)
  for (int i = t; i < 2048; i += 256){
    int r = i >> 4, ch = (i & 15) * 8;
    *(uint4*)(As + r*136 + ch) = *(const uint4*)(Gb + r*128 + ch);
  }
  for (int i = t; i < 2048; i += 256){
    int e = i >> 5, dc = (i & 31) * 4;
    float4 v = *(const float4*)(Wvh + (size_t)e*DD + dc);
    *(ushort4*)(Bs + e*136 + dc) = make_ushort4(f2bf(v.x), f2bf(v.y), f2bf(v.z), f2bf(v.w));
  }
  __syncthreads();
  // phase 1: T[c][e'] ([128]x[64]); wave = 64c x 32e quadrant
  const int wr = (w >> 1)*64, wc = (w & 1)*32;
  f32x4 acc1[4][2] = {};
  for (int kc = 0; kc < 4; ++kc){
    bf16x8 a[4], bb[2];
    #pragma unroll
    for (int r = 0; r < 4; ++r) a[r] = ldfrag_pad(As, wr + r*16, kc, lane);
    #pragma unroll
    for (int c = 0; c < 2; ++c) bb[c] = ldfrag_pad(Bs, wc + c*16, kc, lane);
    #pragma unroll
    for (int r = 0; r < 4; ++r)
      #pragma unroll
      for (int c = 0; c < 2; ++c)
        acc1[r][c] = MFMA_BF16(a[r], bb[c], acc1[r][c], 0, 0, 0);
  }
  __syncthreads();
  // write T^T into Bs [e][c], stage P into As
  #pragma unroll
  for (int r = 0; r < 4; ++r)
    #pragma unroll
    for (int c = 0; c < 2; ++c){
      int e = wc + c*16 + (lane & 15);
      int c0 = wr + r*16 + quad*4;
      *(ushort4*)(Bs + e*136 + c0) = make_ushort4(f2bf(acc1[r][c][0]), f2bf(acc1[r][c][1]),
                                                  f2bf(acc1[r][c][2]), f2bf(acc1[r][c][3]));
    }
  const unsigned short* Ph = Pbf + h*DD*DD;
  for (int i = t; i < 2048; i += 256){
    int r = i >> 4, ch = (i & 15) * 8;
    *(uint4*)(As + r*136 + ch) = *(const uint4*)(Ph + r*128 + ch);
  }
  __syncthreads();
  // phase 2: Mh[d][e'] = P @ T  ([128]x[64])
  f32x4 acc2[4][2] = {};
  for (int kc = 0; kc < 4; ++kc){
    bf16x8 a[4], bb[2];
    #pragma unroll
    for (int r = 0; r < 4; ++r) a[r] = ldfrag_pad(As, wr + r*16, kc, lane);
    #pragma unroll
    for (int c = 0; c < 2; ++c) bb[c] = ldfrag_pad(Bs, wc + c*16, kc, lane);
    #pragma unroll
    for (int r = 0; r < 4; ++r)
      #pragma unroll
      for (int c = 0; c < 2; ++c)
        acc2[r][c] = MFMA_BF16(a[r], bb[c], acc2[r][c], 0, 0, 0);
  }
  __syncthreads();
  // transpose through LDS (float [e][132]) then coalesced copy to Mpt[b][h][e0+e][d]
  float* Af = (float*)As;
  #pragma unroll
  for (int r = 0; r < 4; ++r)
    #pragma unroll
    for (int c = 0; c < 2; ++c){
      int e = wc + c*16 + (lane & 15);
      int d0 = wr + r*16 + quad*4;
      *(float4*)(Af + e*132 + d0) = make_float4(acc2[r][c][0], acc2[r][c][1], acc2[r][c][2], acc2[r][c][3]);
    }
  __syncthreads();
  float* Mb = Mpt + ((size_t)(b*8 + h) << 14);
  for (int i = t; i < 2048; i += 256){
    int e = i >> 5, dc = (i & 31) * 4;
    *(float4*)(Mb + (size_t)(e0 + e)*DD + dc) = *(const float4*)(Af + e*132 + dc);
  }
}

// ---------------- kmr: Mtbf[b][e][d] = bf16( sum_h Mpt[b][h][e][d] ) ----------------
__global__ __launch_bounds__(256) void kmr(const float* __restrict__ Mpt,
                                           unsigned short* __restrict__ Mtbf){
  size_t idx = (size_t)blockIdx.x*1024 + threadIdx.x*4;
  int b = (int)(idx >> 14); int i = (int)(idx & 16383);
  float4 s = make_float4(0.f, 0.f, 0.f, 0.f);
  #pragma unroll
  for (int h = 0; h < 8; ++h){
    float4 v = *(const float4*)(Mpt + ((size_t)(b*8 + h) << 14) + i);
    s.x += v.x; s.y += v.y; s.z += v.z; s.w += v.w;
  }
  *(ushort4*)(Mtbf + idx) = make_ushort4(f2bf(s.x), f2bf(s.y), f2bf(s.z), f2bf(s.w));
}

// ---------------- ko: out[b,ntile] = x_tile @ M[b]  (MFMA, B = Mtbf rows) ----------------
__global__ __launch_bounds__(256) void ko(const float* __restrict__ x,
                                          const unsigned short* __restrict__ Mtbf,
                                          float* __restrict__ out){
  __shared__ __align__(16) unsigned short xs[16384];  // x tile bf16, swizzled [n][d]
  __shared__ __align__(16) unsigned short Ms[16384];  // M^T bf16, swizzled [e][d]
  const int bid = blockIdx.x;
  const int b = bid & 31, nt = bid >> 5;
  const int t = threadIdx.x;
  const int w = t >> 6, lane = t & 63, quad = lane >> 4;
  const float* xb = x + ((size_t)b*NN + (size_t)nt*128)*DD;
  const unsigned short* Mtb = Mtbf + ((size_t)b << 14);
  // stage x (cvt bf16, swizzled) and M^T (16B swizzled copy)
  for (int i = t; i < 4096; i += 256){
    int n = i >> 5, dcq = i & 31;
    float4 v = *(const float4*)(xb + (size_t)n*DD + dcq*4);
    int off = n*128 + ((((dcq >> 1) ^ (n & 7)) << 3) + (dcq & 1)*4);
    *(ushort4*)(xs + off) = make_ushort4(f2bf(v.x), f2bf(v.y), f2bf(v.z), f2bf(v.w));
  }
  for (int i = t; i < 2048; i += 256){
    int e = i >> 4, ng = i & 15;
    *(uint4*)(Ms + e*128 + ((ng ^ (e & 7)) << 3)) = *(const uint4*)(Mtb + e*128 + ng*8);
  }
  __syncthreads();
  const int wr = (w >> 1)*64, wc = (w & 1)*64;
  f32x4 acc[4][4] = {};
  for (int kc = 0; kc < 4; ++kc){
    bf16x8 a[4], bb[4];
    #pragma unroll
    for (int r = 0; r < 4; ++r) a[r] = ldfrag_sw(xs, wr + r*16, kc, lane);
    #pragma unroll
    for (int c = 0; c < 4; ++c) bb[c] = ldfrag_sw(Ms, wc + c*16, kc, lane);
    #pragma unroll
    for (int r = 0; r < 4; ++r)
      #pragma unroll
      for (int c = 0; c < 4; ++c)
        acc[r][c] = MFMA_BF16(a[r], bb[c], acc[r][c], 0, 0, 0);
  }
  float* ob = out + ((size_t)b*NN + (size_t)nt*128)*DD;
  #pragma unroll
  for (int r = 0; r < 4; ++r)
    #pragma unroll
    for (int c = 0; c < 4; ++c)
      #pragma unroll
      for (int reg = 0; reg < 4; ++reg)
        ob[(size_t)(wr + r*16 + quad*4 + reg)*DD + wc + c*16 + (lane & 15)] = acc[r][c][reg];
}

extern "C" void kernel_launch(void* const* d_in, const int* in_sizes, int n_in,
                              void* d_out, int out_size, void* d_ws, size_t ws_size,
                              hipStream_t stream){
  const float* x  = (const float*)d_in[0];
  const float* Wk = (const float*)d_in[1];
  const float* Wq = (const float*)d_in[2];
  const float* Wv = (const float*)d_in[3];
  float* out = (float*)d_out;
  float* ws = (float*)d_ws;
  float* Gp  = ws;                                  // 8388608 floats
  float* Mpt = ws + 8388608;                        // 4194304 floats
  unsigned short* Gbf  = (unsigned short*)(ws + 12582912);  // 524288 ushorts
  unsigned short* Pbf  = Gbf + 524288;                      // 131072 ushorts
  unsigned short* Mtbf = Pbf + 131072;                      // 524288 ushorts

  kgkp<<<544, 256, 0, stream>>>(x, Wq, Wk, Gp, Pbf);
  kgr <<<512, 256, 0, stream>>>(Gp, Gbf);
  km  <<<512, 256, 0, stream>>>(Gbf, Wv, Pbf, Mpt);
  kmr <<<512, 256, 0, stream>>>(Mpt, Mtbf);
  ko  <<<512, 256, 0, stream>>>(x, Mtbf, out);
}